// Round 2
// baseline (575.020 us; speedup 1.0000x reference)
//
#include <hip/hip_runtime.h>
#include <hip/hip_bf16.h>
#include <math.h>

// Problem constants
#define BB 64
#define TT 4096
#define DD 256
#define UU 256
#define MT 32              // timestep tile (MFMA M)
#define NT (TT/MT)         // 128 tiles per batch
#define TPB 8              // tiles processed per block (amortizes W-frag loads)
#define NBLK (BB*NT/TPB)   // 1024 blocks
#define NP (NT/TPB)        // 16 partial blocks per batch
#define LDA 264            // padded LDS row stride in bf16 elems (+8 pad)

typedef __attribute__((ext_vector_type(8))) short bf16x8;
typedef __attribute__((ext_vector_type(4))) float f32x4;

static __device__ __forceinline__ short f2bf(float f){
  unsigned u = __float_as_uint(f);
  u = (u + 0x7fffu + ((u >> 16) & 1u)) >> 16;   // RNE
  return (short)u;
}

// packed fp32x2 -> bf16x2 (RNE); gfx950 has v_cvt_pk_bf16_f32
static __device__ __forceinline__ unsigned pk_bf16(float a, float b){
#if __has_builtin(__builtin_amdgcn_cvt_pk_bf16_f32)
  typedef __bf16 bf16v2 __attribute__((ext_vector_type(2)));
  bf16v2 r = __builtin_amdgcn_cvt_pk_bf16_f32(a, b);
  unsigned u; __builtin_memcpy(&u, &r, 4); return u;
#else
  unsigned ua = __float_as_uint(a), ub = __float_as_uint(b);
  ua = (ua + 0x7fffu + ((ua >> 16) & 1u)) >> 16;
  ub = (ub + 0x7fffu + ((ub >> 16) & 1u)) & 0xffff0000u;
  return ub | ua;
#endif
}

// Kernel 0: W[d][u] fp32 -> pre-swizzled bf16 MFMA B-fragments.
// Frag f = wv*32 + nf*8 + kt; lane l (lo=l&15, quad=l>>4) holds
// u = wv*64+nf*16+lo, d = kt*32+quad*8+j (j=0..7), at Wf[(f*64+l)*8+j].
// Also zeroes the per-batch ticket counters (workspace is poisoned each iter).
__global__ void wfrag_kernel(const float* __restrict__ W, short* __restrict__ Wf,
                             unsigned* __restrict__ cnt){
  if (blockIdx.x == 0 && threadIdx.x < BB) cnt[threadIdx.x] = 0u;
  int g  = blockIdx.x*256 + threadIdx.x;   // 8192 threads = 128 frags * 64 lanes
  int l  = g & 63;
  int f  = g >> 6;
  int kt = f & 7, nf = (f >> 3) & 3, wv = f >> 5;
  int lo = l & 15, quad = l >> 4;
  int u  = wv*64 + nf*16 + lo;
  int d0 = kt*32 + quad*8;
  bf16x8 v;
  #pragma unroll
  for (int j=0;j<8;++j) v[j] = f2bf(W[(size_t)(d0+j)*UU + u]);
  *reinterpret_cast<bf16x8*>(&Wf[(size_t)g*8]) = v;
}

// Kernel 1: each block owns TPB=8 consecutive 32-row tiles of one batch.
// W fragments live in VGPRs for the whole block; X is double-buffered
// (nontemporal reg prefetch issued BEFORE the barrier -> in flight across
// barrier+MFMA); softmax is online across the block's 8 tiles. The last
// block of each batch (ticket) merges the 16 partials in-kernel (split-K).
__global__ __launch_bounds__(256, 2)
void attn_tile_kernel(const float* __restrict__ X, const short* __restrict__ Wf,
                      const float* __restrict__ Wb, const float* __restrict__ Vw,
                      float* __restrict__ m_part, float* __restrict__ l_part,
                      float* __restrict__ ctx_part, unsigned* __restrict__ cnt,
                      float* __restrict__ out)
{
  __shared__ short a_tile[2][MT*LDA];  // 2 x 16896 B bf16 X tile (double buffer)
  __shared__ float s_part[4][MT];      // per-wave logit partials
  __shared__ float s_pw[4][MT];        // per-wave p broadcast (same-wave RAW)
  __shared__ float s_red[8][264];      // ctx 8-group reduction (padded)
  __shared__ unsigned s_tk;            // ticket broadcast

  const int tid  = threadIdx.x;
  const int lane = tid & 63;
  const int wv   = tid >> 6;
  const int lo   = lane & 15;
  const int quad = lane >> 4;
  const int u_base = wv*64 + lo;
  const int blk = blockIdx.x;
  const int b   = blk >> 4;              // batch (16 blocks per batch)
  const int seg = blk & 15;
  const size_t xbase0 = ((size_t)b*TT + (size_t)(seg*TPB)*MT)*DD;
  const int rgrp  = tid >> 5;            // 0..7: row group (4 rows each)
  const int cbase = (tid & 31)*8;        // 8-col chunk

  // ---- prologue: prefetch tile 0 into registers (HBM first, longest latency)
  f32x4 xp[8];
  #pragma unroll
  for (int p8=0; p8<4; ++p8){
    const f32x4* src = reinterpret_cast<const f32x4*>(
        X + xbase0 + (size_t)(p8*8 + rgrp)*DD + cbase);
    xp[p8*2]   = __builtin_nontemporal_load(src);
    xp[p8*2+1] = __builtin_nontemporal_load(src+1);
  }

  float wb_r[4], v_r[4];
  #pragma unroll
  for (int nf=0; nf<4; ++nf){
    wb_r[nf] = Wb[u_base + nf*16];
    v_r[nf]  = Vw[u_base + nf*16];
  }

  // ---- W fragments: load once, keep in registers (32 x bf16x8 = 128 VGPR) ----
  bf16x8 wreg[4][8];
  {
    const short* wf_base = Wf + ((size_t)(wv*32*64 + lane))*8;
    #pragma unroll
    for (int nf=0; nf<4; ++nf)
      #pragma unroll
      for (int kt=0; kt<8; ++kt)
        wreg[nf][kt] = *reinterpret_cast<const bf16x8*>(wf_base + (nf*8 + kt)*512);
  }

  float m_run = -INFINITY, l_run = 0.f;
  float cp[8] = {0.f,0.f,0.f,0.f,0.f,0.f,0.f,0.f};

  for (int it=0; it<TPB; ++it){
    const int buf = it & 1;

    // ---- stage prefetched regs -> bf16 LDS tile ----
    #pragma unroll
    for (int p8=0; p8<4; ++p8){
      int4 v;
      v.x = (int)pk_bf16(xp[p8*2][0],   xp[p8*2][1]);
      v.y = (int)pk_bf16(xp[p8*2][2],   xp[p8*2][3]);
      v.z = (int)pk_bf16(xp[p8*2+1][0], xp[p8*2+1][1]);
      v.w = (int)pk_bf16(xp[p8*2+1][2], xp[p8*2+1][3]);
      *reinterpret_cast<int4*>(&a_tile[buf][(p8*8 + rgrp)*LDA + cbase]) = v;
    }

    // ---- prefetch tile it+1 BEFORE the barrier: xp regs just freed; loads
    // stay in flight across barrier + MFMA (reg loads aren't drained by s_barrier)
    if (it+1 < TPB){
      const size_t xb = xbase0 + (size_t)(it+1)*MT*DD;
      #pragma unroll
      for (int p8=0; p8<4; ++p8){
        const f32x4* src = reinterpret_cast<const f32x4*>(
            X + xb + (size_t)(p8*8 + rgrp)*DD + cbase);
        xp[p8*2]   = __builtin_nontemporal_load(src);
        xp[p8*2+1] = __builtin_nontemporal_load(src+1);
      }
    }
    __syncthreads();

    // ---- MFMA: score[32t x 64u] per wave, K=256 ----
    f32x4 acc[2][4];
    #pragma unroll
    for (int mf=0; mf<2; ++mf)
      #pragma unroll
      for (int nf=0; nf<4; ++nf)
        acc[mf][nf] = (f32x4){0.f,0.f,0.f,0.f};

    #pragma unroll
    for (int kt=0; kt<8; ++kt){
      const int k0 = kt*32 + quad*8;
      bf16x8 af[2];
      #pragma unroll
      for (int mf=0; mf<2; ++mf)
        af[mf] = *reinterpret_cast<const bf16x8*>(&a_tile[buf][(mf*16 + lo)*LDA + k0]);
      #pragma unroll
      for (int nf=0; nf<4; ++nf){
        #pragma unroll
        for (int mf=0; mf<2; ++mf)
          acc[mf][nf] = __builtin_amdgcn_mfma_f32_16x16x32_bf16(af[mf], wreg[nf][kt], acc[mf][nf], 0, 0, 0);
      }
    }

    // ---- epilogue: tanh, dot with V, reduce over this wave's 64 units ----
    // C/D layout: col(u)=lane&15, row(t)=quad*4+reg
    #pragma unroll
    for (int mf=0; mf<2; ++mf){
      #pragma unroll
      for (int r=0; r<4; ++r){
        float part = 0.f;
        #pragma unroll
        for (int nf=0; nf<4; ++nf){
          float s  = acc[mf][nf][r] + wb_r[nf];
          float e2 = __expf(2.f*s);
          float th = 1.f - 2.f/(e2 + 1.f);     // robust tanh
          part = fmaf(th, v_r[nf], part);
        }
        part += __shfl_xor(part, 1);
        part += __shfl_xor(part, 2);
        part += __shfl_xor(part, 4);
        part += __shfl_xor(part, 8);
        if (lo == 0) s_part[wv][mf*16 + quad*4 + r] = part;
      }
    }
    __syncthreads();

    // ---- per-wave redundant softmax over the 32 tile logits + online merge ----
    const int li = lane & 31;
    float lt = s_part[0][li] + s_part[1][li] + s_part[2][li] + s_part[3][li];
    float mx = lt;
    #pragma unroll
    for (int o=16; o; o>>=1) mx = fmaxf(mx, __shfl_xor(mx, o));

    float m_new = fmaxf(m_run, mx);
    float corr  = __expf(m_run - m_new);       // 1 if max unchanged, 0 on first tile
    float p = __expf(lt - m_new);
    float sum = p;
    #pragma unroll
    for (int o=16; o; o>>=1) sum += __shfl_xor(sum, o);
    l_run = l_run * corr + sum;
    s_pw[wv][li] = p;                    // same-wave producer/consumer (dup-safe)

    if (corr != 1.f){                    // wave-uniform: rescale running ctx
      #pragma unroll
      for (int j=0; j<8; ++j) cp[j] *= corr;
    }
    m_run = m_new;

    // ---- ctx accumulate from the bf16 LDS tile ----
    #pragma unroll
    for (int p8=0; p8<4; ++p8){
      float pr = s_pw[wv][p8*8 + rgrp];
      bf16x8 xv = *reinterpret_cast<const bf16x8*>(&a_tile[buf][(p8*8 + rgrp)*LDA + cbase]);
      #pragma unroll
      for (int j=0; j<8; ++j){
        float x = __uint_as_float(((unsigned)(unsigned short)xv[j]) << 16);
        cp[j] = fmaf(pr, x, cp[j]);
      }
    }
  }

  // ---- once per block: 8-group reduction, write partials ----
  *reinterpret_cast<float4*>(&s_red[rgrp][cbase])   = (float4){cp[0],cp[1],cp[2],cp[3]};
  *reinterpret_cast<float4*>(&s_red[rgrp][cbase+4]) = (float4){cp[4],cp[5],cp[6],cp[7]};
  __syncthreads();

  float ctx = 0.f;
  #pragma unroll
  for (int g=0; g<8; ++g) ctx += s_red[g][tid];

  ctx_part[(size_t)blk*DD + tid] = ctx;
  if (tid == 0){ m_part[blk] = m_run; l_part[blk] = l_run; }

  // ---- split-K finisher: last block of this batch merges the 16 partials ----
  __threadfence();                       // release our partials to agent scope
  if (tid == 0)
    s_tk = __hip_atomic_fetch_add(&cnt[b], 1u, __ATOMIC_ACQ_REL,
                                  __HIP_MEMORY_SCOPE_AGENT);
  __syncthreads();
  if (s_tk == NP-1){
    __threadfence();                     // acquire side
    const int base = b*NP;
    float mv[NP];
    float mg = -INFINITY;
    #pragma unroll
    for (int i=0; i<NP; ++i){
      mv[i] = __hip_atomic_load(&m_part[base+i], __ATOMIC_RELAXED,
                                __HIP_MEMORY_SCOPE_AGENT);
      mg = fmaxf(mg, mv[i]);
    }
    float lg = 0.f, s = 0.f;
    #pragma unroll
    for (int i=0; i<NP; ++i){
      float w  = __expf(mv[i] - mg);
      float lv = __hip_atomic_load(&l_part[base+i], __ATOMIC_RELAXED,
                                   __HIP_MEMORY_SCOPE_AGENT);
      float cv = __hip_atomic_load(&ctx_part[(size_t)(base+i)*DD + tid],
                                   __ATOMIC_RELAXED, __HIP_MEMORY_SCOPE_AGENT);
      lg += lv * w;
      s   = fmaf(w, cv, s);
    }
    out[b*DD + tid] = s / lg;
  }
}

extern "C" void kernel_launch(void* const* d_in, const int* in_sizes, int n_in,
                              void* d_out, int out_size, void* d_ws, size_t ws_size,
                              hipStream_t stream)
{
  const float* X  = (const float*)d_in[0];
  const float* Ww = (const float*)d_in[1];
  const float* Wb = (const float*)d_in[2];
  const float* Vw = (const float*)d_in[3];
  // V_b shifts all logits equally -> cancels in softmax; ignored.
  float* out = (float*)d_out;

  // workspace: Wf bf16 frags (128 KB) | m (1024 f) | l (1024 f)
  //          | ctx (1024*256 f) | ticket counters (64 u32)
  short* Wf       = (short*)d_ws;
  float* m_part   = (float*)((char*)d_ws + (size_t)UU*DD*sizeof(short));
  float* l_part   = m_part + NBLK;
  float* ctx_part = l_part + NBLK;
  unsigned* cnt   = (unsigned*)(ctx_part + (size_t)NBLK*DD);

  wfrag_kernel<<<32, 256, 0, stream>>>(Ww, Wf, cnt);
  attn_tile_kernel<<<NBLK, 256, 0, stream>>>(X, Wf, Wb, Vw, m_part, l_part,
                                             ctx_part, cnt, out);
}

// Round 3
// 512.512 us; speedup vs baseline: 1.1220x; 1.1220x over previous
//
#include <hip/hip_runtime.h>
#include <hip/hip_bf16.h>
#include <math.h>

// Problem constants
#define BB 64
#define TT 4096
#define DD 256
#define UU 256
#define MT 32              // timestep tile (MFMA M)
#define NT (TT/MT)         // 128 tiles per batch
#define TPB 8              // tiles processed per block (amortizes W-frag loads)
#define NBLK (BB*NT/TPB)   // 1024 blocks
#define NP (NT/TPB)        // 16 partials per batch
#define LDA 264            // padded LDS row stride in bf16 elems (+8 pad)

typedef __attribute__((ext_vector_type(8))) short bf16x8;
typedef __attribute__((ext_vector_type(4))) float f32x4;

static __device__ __forceinline__ short f2bf(float f){
  unsigned u = __float_as_uint(f);
  u = (u + 0x7fffu + ((u >> 16) & 1u)) >> 16;   // RNE
  return (short)u;
}

// packed fp32x2 -> bf16x2 (RNE); gfx950 has v_cvt_pk_bf16_f32
static __device__ __forceinline__ unsigned pk_bf16(float a, float b){
#if __has_builtin(__builtin_amdgcn_cvt_pk_bf16_f32)
  typedef __bf16 bf16v2 __attribute__((ext_vector_type(2)));
  bf16v2 r = __builtin_amdgcn_cvt_pk_bf16_f32(a, b);
  unsigned u; __builtin_memcpy(&u, &r, 4); return u;
#else
  unsigned ua = __float_as_uint(a), ub = __float_as_uint(b);
  ua = (ua + 0x7fffu + ((ua >> 16) & 1u)) >> 16;
  ub = (ub + 0x7fffu + ((ub >> 16) & 1u)) & 0xffff0000u;
  return ub | ua;
#endif
}

// Kernel 0: W[d][u] fp32 -> pre-swizzled bf16 MFMA B-fragments.
// Frag f = wv*32 + nf*8 + kt; lane l (lo=l&15, quad=l>>4) holds
// u = wv*64+nf*16+lo, d = kt*32+quad*8+j (j=0..7), at Wf[(f*64+l)*8+j].
__global__ void wfrag_kernel(const float* __restrict__ W, short* __restrict__ Wf){
  int g  = blockIdx.x*256 + threadIdx.x;   // 8192 threads = 128 frags * 64 lanes
  int l  = g & 63;
  int f  = g >> 6;
  int kt = f & 7, nf = (f >> 3) & 3, wv = f >> 5;
  int lo = l & 15, quad = l >> 4;
  int u  = wv*64 + nf*16 + lo;
  int d0 = kt*32 + quad*8;
  bf16x8 v;
  #pragma unroll
  for (int j=0;j<8;++j) v[j] = f2bf(W[(size_t)(d0+j)*UU + u]);
  *reinterpret_cast<bf16x8*>(&Wf[(size_t)g*8]) = v;
}

// Kernel 1: each block owns TPB=8 consecutive 32-row tiles of one batch.
// W fragments live in VGPRs for the whole block (loaded once, 128 VGPR/wave);
// X is double-buffered: prefetch issued AFTER the barrier (loads in flight
// under MFMA+epilogue; issuing before the barrier stalls on the compiler's
// vmcnt(0) drain at s_barrier — measured 6x regression in round 2).
// Softmax is online across the block's 8 tiles. s_red overlays a_tile[0]
// (used only after the loop; last iteration reads a_tile[1], and two
// barriers separate the last a_tile[0] read from the overlay writes) ->
// LDS ~34.8 KB -> 4 blocks/CU resident.
__global__ __launch_bounds__(256, 4)
void attn_tile_kernel(const float* __restrict__ X, const short* __restrict__ Wf,
                      const float* __restrict__ Wb, const float* __restrict__ Vw,
                      float* __restrict__ m_part, float* __restrict__ l_part,
                      float* __restrict__ ctx_part)
{
  __shared__ short a_tile[2][MT*LDA];  // 2 x 16896 B bf16 X tile (double buffer)
  __shared__ float s_part[4][MT];      // per-wave logit partials
  __shared__ float s_pw[4][MT];        // per-wave p broadcast (same-wave RAW)
  // ctx 8-group reduction (8x264 f32 = 8448 B) overlays a_tile[0] (16896 B)
  float* s_red = reinterpret_cast<float*>(&a_tile[0][0]);

  const int tid  = threadIdx.x;
  const int lane = tid & 63;
  const int wv   = tid >> 6;
  const int lo   = lane & 15;
  const int quad = lane >> 4;
  const int u_base = wv*64 + lo;
  const int blk = blockIdx.x;
  const int b   = blk >> 4;              // batch (16 blocks per batch)
  const int seg = blk & 15;
  const size_t xbase0 = ((size_t)b*TT + (size_t)(seg*TPB)*MT)*DD;
  const int rgrp  = tid >> 5;            // 0..7: row group (4 rows each)
  const int cbase = (tid & 31)*8;        // 8-col chunk

  float wb_r[4], v_r[4];
  #pragma unroll
  for (int nf=0; nf<4; ++nf){
    wb_r[nf] = Wb[u_base + nf*16];
    v_r[nf]  = Vw[u_base + nf*16];
  }

  // ---- W fragments: load once, keep in registers (32 x bf16x8 = 128 VGPR) ----
  bf16x8 wreg[4][8];
  {
    const short* wf_base = Wf + ((size_t)(wv*32*64 + lane))*8;
    #pragma unroll
    for (int nf=0; nf<4; ++nf)
      #pragma unroll
      for (int kt=0; kt<8; ++kt)
        wreg[nf][kt] = *reinterpret_cast<const bf16x8*>(wf_base + (nf*8 + kt)*512);
  }

  // ---- prologue: prefetch tile 0 into registers ----
  float4 xp[8];
  #pragma unroll
  for (int p8=0; p8<4; ++p8){
    const float4* src = reinterpret_cast<const float4*>(
        X + xbase0 + (size_t)(p8*8 + rgrp)*DD + cbase);
    xp[p8*2]   = src[0];
    xp[p8*2+1] = src[1];
  }

  float m_run = -INFINITY, l_run = 0.f;
  float cp[8] = {0.f,0.f,0.f,0.f,0.f,0.f,0.f,0.f};

  for (int it=0; it<TPB; ++it){
    const int buf = it & 1;

    // ---- stage prefetched regs -> bf16 LDS tile ----
    #pragma unroll
    for (int p8=0; p8<4; ++p8){
      int4 v;
      v.x = (int)pk_bf16(xp[p8*2].x,   xp[p8*2].y);
      v.y = (int)pk_bf16(xp[p8*2].z,   xp[p8*2].w);
      v.z = (int)pk_bf16(xp[p8*2+1].x, xp[p8*2+1].y);
      v.w = (int)pk_bf16(xp[p8*2+1].z, xp[p8*2+1].w);
      *reinterpret_cast<int4*>(&a_tile[buf][(p8*8 + rgrp)*LDA + cbase]) = v;
    }
    __syncthreads();

    // ---- prefetch tile it+1 (in flight under MFMA + epilogue) ----
    if (it+1 < TPB){
      const size_t xb = xbase0 + (size_t)(it+1)*MT*DD;
      #pragma unroll
      for (int p8=0; p8<4; ++p8){
        const float4* src = reinterpret_cast<const float4*>(
            X + xb + (size_t)(p8*8 + rgrp)*DD + cbase);
        xp[p8*2]   = src[0];
        xp[p8*2+1] = src[1];
      }
    }

    // ---- MFMA: score[32t x 64u] per wave, K=256 ----
    f32x4 acc[2][4];
    #pragma unroll
    for (int mf=0; mf<2; ++mf)
      #pragma unroll
      for (int nf=0; nf<4; ++nf)
        acc[mf][nf] = (f32x4){0.f,0.f,0.f,0.f};

    #pragma unroll
    for (int kt=0; kt<8; ++kt){
      const int k0 = kt*32 + quad*8;
      bf16x8 af[2];
      #pragma unroll
      for (int mf=0; mf<2; ++mf)
        af[mf] = *reinterpret_cast<const bf16x8*>(&a_tile[buf][(mf*16 + lo)*LDA + k0]);
      #pragma unroll
      for (int nf=0; nf<4; ++nf){
        #pragma unroll
        for (int mf=0; mf<2; ++mf)
          acc[mf][nf] = __builtin_amdgcn_mfma_f32_16x16x32_bf16(af[mf], wreg[nf][kt], acc[mf][nf], 0, 0, 0);
      }
    }

    // ---- epilogue: tanh, dot with V, reduce over this wave's 64 units ----
    // C/D layout: col(u)=lane&15, row(t)=quad*4+reg
    #pragma unroll
    for (int mf=0; mf<2; ++mf){
      #pragma unroll
      for (int r=0; r<4; ++r){
        float part = 0.f;
        #pragma unroll
        for (int nf=0; nf<4; ++nf){
          float s  = acc[mf][nf][r] + wb_r[nf];
          float e2 = __expf(2.f*s);
          float th = 1.f - 2.f/(e2 + 1.f);     // robust tanh
          part = fmaf(th, v_r[nf], part);
        }
        part += __shfl_xor(part, 1);
        part += __shfl_xor(part, 2);
        part += __shfl_xor(part, 4);
        part += __shfl_xor(part, 8);
        if (lo == 0) s_part[wv][mf*16 + quad*4 + r] = part;
      }
    }
    __syncthreads();

    // ---- per-wave redundant softmax over the 32 tile logits + online merge ----
    const int li = lane & 31;
    float lt = s_part[0][li] + s_part[1][li] + s_part[2][li] + s_part[3][li];
    float mx = lt;
    #pragma unroll
    for (int o=16; o; o>>=1) mx = fmaxf(mx, __shfl_xor(mx, o));

    float m_new = fmaxf(m_run, mx);
    float corr  = __expf(m_run - m_new);       // 1 if max unchanged, 0 on first tile
    float p = __expf(lt - m_new);
    float sum = p;
    #pragma unroll
    for (int o=16; o; o>>=1) sum += __shfl_xor(sum, o);
    l_run = l_run * corr + sum;
    s_pw[wv][li] = p;                    // same-wave producer/consumer (dup-safe)

    if (corr != 1.f){                    // wave-uniform: rescale running ctx
      #pragma unroll
      for (int j=0; j<8; ++j) cp[j] *= corr;
    }
    m_run = m_new;

    // ---- ctx accumulate from the bf16 LDS tile ----
    #pragma unroll
    for (int p8=0; p8<4; ++p8){
      float pr = s_pw[wv][p8*8 + rgrp];
      bf16x8 xv = *reinterpret_cast<const bf16x8*>(&a_tile[buf][(p8*8 + rgrp)*LDA + cbase]);
      #pragma unroll
      for (int j=0; j<8; ++j){
        float x = __uint_as_float(((unsigned)(unsigned short)xv[j]) << 16);
        cp[j] = fmaf(pr, x, cp[j]);
      }
    }
  }

  // ---- once per block: 8-group reduction (overlay on a_tile[0]), write partials
  // Safe: last loop iteration (it=7) read a_tile[1]; the last a_tile[0] read
  // (it=6 ctx accumulate) is separated from these writes by it=7's barriers.
  *reinterpret_cast<float4*>(&s_red[rgrp*264 + cbase])     = (float4){cp[0],cp[1],cp[2],cp[3]};
  *reinterpret_cast<float4*>(&s_red[rgrp*264 + cbase + 4]) = (float4){cp[4],cp[5],cp[6],cp[7]};
  __syncthreads();

  float ctx = 0.f;
  #pragma unroll
  for (int g=0; g<8; ++g) ctx += s_red[g*264 + tid];

  if (tid == 0){ m_part[blk] = m_run; l_part[blk] = l_run; }
  ctx_part[(size_t)blk*DD + tid] = ctx;
}

// Kernel 2: merge the 16 block partials per batch with max-rescaling.
__global__ __launch_bounds__(256)
void merge_kernel(const float* __restrict__ m_part, const float* __restrict__ l_part,
                  const float* __restrict__ ctx_part, float* __restrict__ out)
{
  const int b = blockIdx.x;
  const int d = threadIdx.x;

  float mg = -INFINITY;
  #pragma unroll
  for (int i=0; i<NP; ++i) mg = fmaxf(mg, m_part[b*NP+i]);

  float lg = 0.f, s = 0.f;
  #pragma unroll
  for (int i=0; i<NP; ++i){
    float w = __expf(m_part[b*NP+i] - mg);
    lg += l_part[b*NP+i] * w;
    s   = fmaf(w, ctx_part[(size_t)(b*NP+i)*DD + d], s);
  }
  out[b*DD + d] = s / lg;
}

extern "C" void kernel_launch(void* const* d_in, const int* in_sizes, int n_in,
                              void* d_out, int out_size, void* d_ws, size_t ws_size,
                              hipStream_t stream)
{
  const float* X  = (const float*)d_in[0];
  const float* Ww = (const float*)d_in[1];
  const float* Wb = (const float*)d_in[2];
  const float* Vw = (const float*)d_in[3];
  // V_b shifts all logits equally -> cancels in softmax; ignored.
  float* out = (float*)d_out;

  // workspace: Wf bf16 frags (128 KB) | m (1024 f) | l (1024 f) | ctx (1024*256 f)
  short* Wf       = (short*)d_ws;
  float* m_part   = (float*)((char*)d_ws + (size_t)UU*DD*sizeof(short));
  float* l_part   = m_part + NBLK;
  float* ctx_part = l_part + NBLK;

  wfrag_kernel<<<32, 256, 0, stream>>>(Ww, Wf);
  attn_tile_kernel<<<NBLK, 256, 0, stream>>>(X, Wf, Wb, Vw, m_part, l_part, ctx_part);
  merge_kernel<<<BB, 256, 0, stream>>>(m_part, l_part, ctx_part, out);
}

// Round 4
// 381.005 us; speedup vs baseline: 1.5092x; 1.3452x over previous
//
#include <hip/hip_runtime.h>
#include <hip/hip_bf16.h>
#include <math.h>

// Problem constants
#define BB 64
#define TT 4096
#define DD 256
#define UU 256
#define MT 32              // timestep tile (MFMA M)
#define NT (TT/MT)         // 128 tiles per batch
#define TPB 8              // tiles processed per block (amortizes W-frag loads)
#define NBLK (BB*NT/TPB)   // 1024 blocks
#define NP (NT/TPB)        // 16 partials per batch
#define LDA 264            // padded LDS row stride in bf16 elems (+8 pad)

typedef __attribute__((ext_vector_type(8))) short bf16x8;
typedef __attribute__((ext_vector_type(4))) float f32x4;

static __device__ __forceinline__ short f2bf(float f){
  unsigned u = __float_as_uint(f);
  u = (u + 0x7fffu + ((u >> 16) & 1u)) >> 16;   // RNE
  return (short)u;
}

// packed fp32x2 -> bf16x2 (RNE); gfx950 has v_cvt_pk_bf16_f32
static __device__ __forceinline__ unsigned pk_bf16(float a, float b){
#if __has_builtin(__builtin_amdgcn_cvt_pk_bf16_f32)
  typedef __bf16 bf16v2 __attribute__((ext_vector_type(2)));
  bf16v2 r = __builtin_amdgcn_cvt_pk_bf16_f32(a, b);
  unsigned u; __builtin_memcpy(&u, &r, 4); return u;
#else
  unsigned ua = __float_as_uint(a), ub = __float_as_uint(b);
  ua = (ua + 0x7fffu + ((ua >> 16) & 1u)) >> 16;
  ub = (ub + 0x7fffu + ((ub >> 16) & 1u)) & 0xffff0000u;
  return ub | ua;
#endif
}

// Kernel 0: W[d][u] fp32 -> pre-swizzled bf16 MFMA B-fragments.
// Frag f = wv*32 + nf*8 + kt; lane l (lo=l&15, quad=l>>4) holds
// u = wv*64+nf*16+lo, d = kt*32+quad*8+j (j=0..7), at Wf[(f*64+l)*8+j].
__global__ void wfrag_kernel(const float* __restrict__ W, short* __restrict__ Wf){
  int g  = blockIdx.x*256 + threadIdx.x;   // 8192 threads = 128 frags * 64 lanes
  int l  = g & 63;
  int f  = g >> 6;
  int kt = f & 7, nf = (f >> 3) & 3, wv = f >> 5;
  int lo = l & 15, quad = l >> 4;
  int u  = wv*64 + nf*16 + lo;
  int d0 = kt*32 + quad*8;
  bf16x8 v;
  #pragma unroll
  for (int j=0;j<8;++j) v[j] = f2bf(W[(size_t)(d0+j)*UU + u]);
  *reinterpret_cast<bf16x8*>(&Wf[(size_t)g*8]) = v;
}

// Kernel 1: each block owns TPB=8 consecutive 32-row tiles of one batch.
// W fragments live in VGPRs for the whole block (loaded once, 128 VGPR/wave);
// X is double-buffered: prefetch issued AFTER the barrier (loads in flight
// under MFMA+epilogue; issuing before the barrier stalls on the compiler's
// vmcnt(0) drain at s_barrier — measured 6x regression in round 2).
// Softmax is online across the block's 8 tiles. s_red overlays a_tile[0]
// (used only after the loop; last iteration reads a_tile[1], and two
// barriers separate the last a_tile[0] read from the overlay writes) ->
// LDS ~34.8 KB.
// __launch_bounds__(256,2): MUST stay at 2 — bound 4 caps VGPR below the
// 128-reg wreg working set and spills (round 3: VGPR 64, WRITE_SIZE 133 MB,
// attn 250 us). With 128 VGPR + 34.8 KB LDS the HW occupancy limit is
// 4 blocks/CU anyway; the bound only needs to not constrain the allocator.
__global__ __launch_bounds__(256, 2)
void attn_tile_kernel(const float* __restrict__ X, const short* __restrict__ Wf,
                      const float* __restrict__ Wb, const float* __restrict__ Vw,
                      float* __restrict__ m_part, float* __restrict__ l_part,
                      float* __restrict__ ctx_part)
{
  __shared__ short a_tile[2][MT*LDA];  // 2 x 16896 B bf16 X tile (double buffer)
  __shared__ float s_part[4][MT];      // per-wave logit partials
  __shared__ float s_pw[4][MT];        // per-wave p broadcast (same-wave RAW)
  // ctx 8-group reduction (8x264 f32 = 8448 B) overlays a_tile[0] (16896 B)
  float* s_red = reinterpret_cast<float*>(&a_tile[0][0]);

  const int tid  = threadIdx.x;
  const int lane = tid & 63;
  const int wv   = tid >> 6;
  const int lo   = lane & 15;
  const int quad = lane >> 4;
  const int u_base = wv*64 + lo;
  const int blk = blockIdx.x;
  const int b   = blk >> 4;              // batch (16 blocks per batch)
  const int seg = blk & 15;
  const size_t xbase0 = ((size_t)b*TT + (size_t)(seg*TPB)*MT)*DD;
  const int rgrp  = tid >> 5;            // 0..7: row group (4 rows each)
  const int cbase = (tid & 31)*8;        // 8-col chunk

  float wb_r[4], v_r[4];
  #pragma unroll
  for (int nf=0; nf<4; ++nf){
    wb_r[nf] = Wb[u_base + nf*16];
    v_r[nf]  = Vw[u_base + nf*16];
  }

  // ---- W fragments: load once, keep in registers (32 x bf16x8 = 128 VGPR) ----
  bf16x8 wreg[4][8];
  {
    const short* wf_base = Wf + ((size_t)(wv*32*64 + lane))*8;
    #pragma unroll
    for (int nf=0; nf<4; ++nf)
      #pragma unroll
      for (int kt=0; kt<8; ++kt)
        wreg[nf][kt] = *reinterpret_cast<const bf16x8*>(wf_base + (nf*8 + kt)*512);
  }

  // ---- prologue: prefetch tile 0 into registers ----
  float4 xp[8];
  #pragma unroll
  for (int p8=0; p8<4; ++p8){
    const float4* src = reinterpret_cast<const float4*>(
        X + xbase0 + (size_t)(p8*8 + rgrp)*DD + cbase);
    xp[p8*2]   = src[0];
    xp[p8*2+1] = src[1];
  }

  float m_run = -INFINITY, l_run = 0.f;
  float cp[8] = {0.f,0.f,0.f,0.f,0.f,0.f,0.f,0.f};

  for (int it=0; it<TPB; ++it){
    const int buf = it & 1;

    // ---- stage prefetched regs -> bf16 LDS tile ----
    #pragma unroll
    for (int p8=0; p8<4; ++p8){
      int4 v;
      v.x = (int)pk_bf16(xp[p8*2].x,   xp[p8*2].y);
      v.y = (int)pk_bf16(xp[p8*2].z,   xp[p8*2].w);
      v.z = (int)pk_bf16(xp[p8*2+1].x, xp[p8*2+1].y);
      v.w = (int)pk_bf16(xp[p8*2+1].z, xp[p8*2+1].w);
      *reinterpret_cast<int4*>(&a_tile[buf][(p8*8 + rgrp)*LDA + cbase]) = v;
    }
    __syncthreads();

    // ---- prefetch tile it+1 (in flight under MFMA + epilogue) ----
    if (it+1 < TPB){
      const size_t xb = xbase0 + (size_t)(it+1)*MT*DD;
      #pragma unroll
      for (int p8=0; p8<4; ++p8){
        const float4* src = reinterpret_cast<const float4*>(
            X + xb + (size_t)(p8*8 + rgrp)*DD + cbase);
        xp[p8*2]   = src[0];
        xp[p8*2+1] = src[1];
      }
    }

    // ---- MFMA: score[32t x 64u] per wave, K=256 ----
    f32x4 acc[2][4];
    #pragma unroll
    for (int mf=0; mf<2; ++mf)
      #pragma unroll
      for (int nf=0; nf<4; ++nf)
        acc[mf][nf] = (f32x4){0.f,0.f,0.f,0.f};

    #pragma unroll
    for (int kt=0; kt<8; ++kt){
      const int k0 = kt*32 + quad*8;
      bf16x8 af[2];
      #pragma unroll
      for (int mf=0; mf<2; ++mf)
        af[mf] = *reinterpret_cast<const bf16x8*>(&a_tile[buf][(mf*16 + lo)*LDA + k0]);
      #pragma unroll
      for (int nf=0; nf<4; ++nf){
        #pragma unroll
        for (int mf=0; mf<2; ++mf)
          acc[mf][nf] = __builtin_amdgcn_mfma_f32_16x16x32_bf16(af[mf], wreg[nf][kt], acc[mf][nf], 0, 0, 0);
      }
    }

    // ---- epilogue: tanh, dot with V, reduce over this wave's 64 units ----
    // C/D layout: col(u)=lane&15, row(t)=quad*4+reg
    #pragma unroll
    for (int mf=0; mf<2; ++mf){
      #pragma unroll
      for (int r=0; r<4; ++r){
        float part = 0.f;
        #pragma unroll
        for (int nf=0; nf<4; ++nf){
          float s  = acc[mf][nf][r] + wb_r[nf];
          float e2 = __expf(2.f*s);
          float th = 1.f - 2.f/(e2 + 1.f);     // robust tanh
          part = fmaf(th, v_r[nf], part);
        }
        part += __shfl_xor(part, 1);
        part += __shfl_xor(part, 2);
        part += __shfl_xor(part, 4);
        part += __shfl_xor(part, 8);
        if (lo == 0) s_part[wv][mf*16 + quad*4 + r] = part;
      }
    }
    __syncthreads();

    // ---- per-wave redundant softmax over the 32 tile logits + online merge ----
    const int li = lane & 31;
    float lt = s_part[0][li] + s_part[1][li] + s_part[2][li] + s_part[3][li];
    float mx = lt;
    #pragma unroll
    for (int o=16; o; o>>=1) mx = fmaxf(mx, __shfl_xor(mx, o));

    float m_new = fmaxf(m_run, mx);
    float corr  = __expf(m_run - m_new);       // 1 if max unchanged, 0 on first tile
    float p = __expf(lt - m_new);
    float sum = p;
    #pragma unroll
    for (int o=16; o; o>>=1) sum += __shfl_xor(sum, o);
    l_run = l_run * corr + sum;
    s_pw[wv][li] = p;                    // same-wave producer/consumer (dup-safe)

    if (corr != 1.f){                    // wave-uniform: rescale running ctx
      #pragma unroll
      for (int j=0; j<8; ++j) cp[j] *= corr;
    }
    m_run = m_new;

    // ---- ctx accumulate from the bf16 LDS tile ----
    #pragma unroll
    for (int p8=0; p8<4; ++p8){
      float pr = s_pw[wv][p8*8 + rgrp];
      bf16x8 xv = *reinterpret_cast<const bf16x8*>(&a_tile[buf][(p8*8 + rgrp)*LDA + cbase]);
      #pragma unroll
      for (int j=0; j<8; ++j){
        float x = __uint_as_float(((unsigned)(unsigned short)xv[j]) << 16);
        cp[j] = fmaf(pr, x, cp[j]);
      }
    }
  }

  // ---- once per block: 8-group reduction (overlay on a_tile[0]), write partials
  // Safe: last loop iteration (it=7) read a_tile[1]; the last a_tile[0] read
  // (it=6 ctx accumulate) is separated from these writes by it=7's barriers.
  *reinterpret_cast<float4*>(&s_red[rgrp*264 + cbase])     = (float4){cp[0],cp[1],cp[2],cp[3]};
  *reinterpret_cast<float4*>(&s_red[rgrp*264 + cbase + 4]) = (float4){cp[4],cp[5],cp[6],cp[7]};
  __syncthreads();

  float ctx = 0.f;
  #pragma unroll
  for (int g=0; g<8; ++g) ctx += s_red[g*264 + tid];

  if (tid == 0){ m_part[blk] = m_run; l_part[blk] = l_run; }
  ctx_part[(size_t)blk*DD + tid] = ctx;
}

// Kernel 2: merge the 16 block partials per batch with max-rescaling.
__global__ __launch_bounds__(256)
void merge_kernel(const float* __restrict__ m_part, const float* __restrict__ l_part,
                  const float* __restrict__ ctx_part, float* __restrict__ out)
{
  const int b = blockIdx.x;
  const int d = threadIdx.x;

  float mg = -INFINITY;
  #pragma unroll
  for (int i=0; i<NP; ++i) mg = fmaxf(mg, m_part[b*NP+i]);

  float lg = 0.f, s = 0.f;
  #pragma unroll
  for (int i=0; i<NP; ++i){
    float w = __expf(m_part[b*NP+i] - mg);
    lg += l_part[b*NP+i] * w;
    s   = fmaf(w, ctx_part[(size_t)(b*NP+i)*DD + d], s);
  }
  out[b*DD + d] = s / lg;
}

extern "C" void kernel_launch(void* const* d_in, const int* in_sizes, int n_in,
                              void* d_out, int out_size, void* d_ws, size_t ws_size,
                              hipStream_t stream)
{
  const float* X  = (const float*)d_in[0];
  const float* Ww = (const float*)d_in[1];
  const float* Wb = (const float*)d_in[2];
  const float* Vw = (const float*)d_in[3];
  // V_b shifts all logits equally -> cancels in softmax; ignored.
  float* out = (float*)d_out;

  // workspace: Wf bf16 frags (128 KB) | m (1024 f) | l (1024 f) | ctx (1024*256 f)
  short* Wf       = (short*)d_ws;
  float* m_part   = (float*)((char*)d_ws + (size_t)UU*DD*sizeof(short));
  float* l_part   = m_part + NBLK;
  float* ctx_part = l_part + NBLK;

  wfrag_kernel<<<32, 256, 0, stream>>>(Ww, Wf);
  attn_tile_kernel<<<NBLK, 256, 0, stream>>>(X, Wf, Wb, Vw, m_part, l_part, ctx_part);
  merge_kernel<<<BB, 256, 0, stream>>>(m_part, l_part, ctx_part, out);
}